// Round 3
// baseline (262.646 us; speedup 1.0000x reference)
//
#include <hip/hip_runtime.h>
#include <math.h>

#define D 2048
#define NE 64
#define NTOK 16384
#define KSPLIT 4
#define KRANGE (D / KSPLIT)     /* 512 */
#define CHUNK 64                /* k per staging chunk */
#define NCHUNK (KRANGE / CHUNK) /* 8 */
#define TBLK 64                 /* tokens per block */
#define XSTRIDE 65              /* pad: conflict-free transposed writes */
#define LN_EPS 1e-5f

// ---------------- Kernel A: LayerNorm the expert table, store TRANSPOSED ----------------
__global__ __launch_bounds__(256) void expert_ln_kernel(
    const float* __restrict__ emb, float* __restrict__ eT) {
  const int e = blockIdx.x;
  const int tid = threadIdx.x;
  const float4* row = (const float4*)(emb + (size_t)e * D);
  float4 v0 = row[tid * 2];
  float4 v1 = row[tid * 2 + 1];
  float s = v0.x + v0.y + v0.z + v0.w + v1.x + v1.y + v1.z + v1.w;
  float q = v0.x * v0.x + v0.y * v0.y + v0.z * v0.z + v0.w * v0.w
          + v1.x * v1.x + v1.y * v1.y + v1.z * v1.z + v1.w * v1.w;
  #pragma unroll
  for (int off = 32; off > 0; off >>= 1) {
    s += __shfl_down(s, off);
    q += __shfl_down(q, off);
  }
  __shared__ float red[8];
  const int wid = tid >> 6;
  const int lane = tid & 63;
  if (lane == 0) { red[wid] = s; red[4 + wid] = q; }
  __syncthreads();
  if (tid == 0) {
    red[0] = red[0] + red[1] + red[2] + red[3];
    red[4] = red[4] + red[5] + red[6] + red[7];
  }
  __syncthreads();
  const float mu = red[0] * (1.0f / D);
  const float var = red[4] * (1.0f / D) - mu * mu;
  const float sc = rsqrtf(var + LN_EPS);
  float vals[8] = {v0.x, v0.y, v0.z, v0.w, v1.x, v1.y, v1.z, v1.w};
  const int k0 = tid * 8;
  #pragma unroll
  for (int j = 0; j < 8; ++j) {
    eT[(size_t)(k0 + j) * NE + e] = (vals[j] - mu) * sc;
  }
}

// ---------------- Kernel B: K-split GEMM, lane=token / e via uniform loads ----------------
// Grid: KSPLIT * (NTOK/TBLK) = 1024 blocks of 256 threads (4 waves).
// kc in HIGH bits of blockIdx: consecutive blocks share the same eT K-slice
// (better L1/L2 locality for the wave-uniform e-loads).
// Each wave: all 64 tokens (lane = token) x 16 experts (wave id picks slice).
// Inner loop per k: 1 conflict-free ds_read_b32 (x) + 16 FMA; e comes from
// wave-uniform addresses (readfirstlane) -> broadcast loads, no LDS traffic.
__global__ __launch_bounds__(256, 4) void router_gemm_kernel(
    const float* __restrict__ x, const float* __restrict__ eT,
    float* __restrict__ dotP, float* __restrict__ sumP,
    float* __restrict__ sumsqP) {
  __shared__ float xT[CHUNK][XSTRIDE];
  const int tid = threadIdx.x;
  const int bt = blockIdx.x & 255;  // token tile
  const int kc = blockIdx.x >> 8;   // K-slice (consecutive blocks share it)
  const int K0 = kc * KRANGE;
  const int lane = tid & 63;                                  // token for compute
  const int wv = __builtin_amdgcn_readfirstlane(tid >> 6);    // expert slice, uniform
  const int ts = tid >> 2;                                    // staging token 0..63
  const int kb = tid & 3;                                     // staging k-block (16 k)

  float acc[16];
  #pragma unroll
  for (int j = 0; j < 16; ++j) acc[j] = 0.f;
  float s1 = 0.f, s2 = 0.f;

  const float* xrow = x + (size_t)(bt * TBLK + ts) * D + K0 + kb * 16;

  for (int c = 0; c < NCHUNK; ++c) {
    // prefetch the 16 k-values this thread stages (before the barrier)
    float4 v[4];
    #pragma unroll
    for (int j = 0; j < 4; ++j) v[j] = *(const float4*)(xrow + c * CHUNK + j * 4);
    __syncthreads();  // everyone done reading previous chunk
    #pragma unroll
    for (int j = 0; j < 4; ++j) {
      s1 += v[j].x + v[j].y + v[j].z + v[j].w;
      s2 += v[j].x * v[j].x + v[j].y * v[j].y + v[j].z * v[j].z + v[j].w * v[j].w;
      const int kr = kb * 16 + j * 4;
      xT[kr + 0][ts] = v[j].x;
      xT[kr + 1][ts] = v[j].y;
      xT[kr + 2][ts] = v[j].z;
      xT[kr + 3][ts] = v[j].w;
    }
    __syncthreads();
    const float* ep = eT + (size_t)(K0 + c * CHUNK) * NE + wv * 16;
    #pragma unroll 4
    for (int kk = 0; kk < CHUNK; ++kk) {
      const float xv = xT[kk][lane];
      const float4 e0 = *(const float4*)(ep + (size_t)kk * NE + 0);
      const float4 e1 = *(const float4*)(ep + (size_t)kk * NE + 4);
      const float4 e2 = *(const float4*)(ep + (size_t)kk * NE + 8);
      const float4 e3 = *(const float4*)(ep + (size_t)kk * NE + 12);
      acc[0]  = fmaf(e0.x, xv, acc[0]);
      acc[1]  = fmaf(e0.y, xv, acc[1]);
      acc[2]  = fmaf(e0.z, xv, acc[2]);
      acc[3]  = fmaf(e0.w, xv, acc[3]);
      acc[4]  = fmaf(e1.x, xv, acc[4]);
      acc[5]  = fmaf(e1.y, xv, acc[5]);
      acc[6]  = fmaf(e1.z, xv, acc[6]);
      acc[7]  = fmaf(e1.w, xv, acc[7]);
      acc[8]  = fmaf(e2.x, xv, acc[8]);
      acc[9]  = fmaf(e2.y, xv, acc[9]);
      acc[10] = fmaf(e2.z, xv, acc[10]);
      acc[11] = fmaf(e2.w, xv, acc[11]);
      acc[12] = fmaf(e3.x, xv, acc[12]);
      acc[13] = fmaf(e3.y, xv, acc[13]);
      acc[14] = fmaf(e3.z, xv, acc[14]);
      acc[15] = fmaf(e3.w, xv, acc[15]);
    }
  }

  // token stats reduction (4 staging threads per token)
  __syncthreads();
  float* red = &xT[0][0];
  red[kb * 64 + ts] = s1;
  red[256 + kb * 64 + ts] = s2;
  __syncthreads();
  if (tid < TBLK) {
    const int gt = bt * TBLK + tid;
    sumP[kc * NTOK + gt] = red[tid] + red[64 + tid] + red[128 + tid] + red[192 + tid];
    sumsqP[kc * NTOK + gt] =
        red[256 + tid] + red[320 + tid] + red[384 + tid] + red[448 + tid];
  }

  // dot partials: [kc][token][expert]
  float* dp = dotP + ((size_t)kc * NTOK + (size_t)bt * TBLK + lane) * NE + wv * 16;
  *(float4*)(dp + 0)  = make_float4(acc[0], acc[1], acc[2], acc[3]);
  *(float4*)(dp + 4)  = make_float4(acc[4], acc[5], acc[6], acc[7]);
  *(float4*)(dp + 8)  = make_float4(acc[8], acc[9], acc[10], acc[11]);
  *(float4*)(dp + 12) = make_float4(acc[12], acc[13], acc[14], acc[15]);
}

// ---------------- Kernel C: reduce partials, top-2, softmax gates ----------------
// 8 lanes per token; 32 tokens per 256-thread block; grid = 512 blocks.
__global__ __launch_bounds__(256) void finalize_kernel(
    const float* __restrict__ dotP, const float* __restrict__ sumP,
    const float* __restrict__ sumsqP, float* __restrict__ out) {
  const int tid = threadIdx.x;
  const int t = blockIdx.x * 32 + (tid >> 3);
  const int l8 = tid & 7;

  float s1 = 0.f, s2 = 0.f;
  #pragma unroll
  for (int kc = 0; kc < KSPLIT; ++kc) {
    s1 += sumP[kc * NTOK + t];
    s2 += sumsqP[kc * NTOK + t];
  }
  const float mu = s1 * (1.0f / D);
  const float var = s2 * (1.0f / D) - mu * mu;
  const float sc = rsqrtf(var + LN_EPS);  // sim = dot * sc (sum(e_norm)==0)

  float d[8] = {0.f, 0.f, 0.f, 0.f, 0.f, 0.f, 0.f, 0.f};
  #pragma unroll
  for (int kc = 0; kc < KSPLIT; ++kc) {
    const float* dp = dotP + ((size_t)kc * NTOK + t) * NE + l8 * 8;
    float4 a = *(const float4*)dp;
    float4 b = *(const float4*)(dp + 4);
    d[0] += a.x; d[1] += a.y; d[2] += a.z; d[3] += a.w;
    d[4] += b.x; d[5] += b.y; d[6] += b.z; d[7] += b.w;
  }

  float w1 = -INFINITY, w2 = -INFINITY;
  int i1 = 0, i2 = 0;
  #pragma unroll
  for (int j = 0; j < 8; ++j) {
    const float v = d[j] * sc;
    const int e = l8 * 8 + j;
    if (v > w1) { w2 = w1; i2 = i1; w1 = v; i1 = e; }
    else if (v > w2) { w2 = v; i2 = e; }
  }
  // butterfly merge of (top1, top2) across the 8 lanes of this token
  #pragma unroll
  for (int off = 1; off < 8; off <<= 1) {
    const float ow1 = __shfl_xor(w1, off);
    const float ow2 = __shfl_xor(w2, off);
    const int oi1 = __shfl_xor(i1, off);
    const int oi2 = __shfl_xor(i2, off);
    if (ow1 > w1 || (ow1 == w1 && oi1 < i1)) {
      float nw2; int ni2;
      if (w1 > ow2 || (w1 == ow2 && i1 < oi2)) { nw2 = w1; ni2 = i1; }
      else { nw2 = ow2; ni2 = oi2; }
      w1 = ow1; i1 = oi1; w2 = nw2; i2 = ni2;
    } else {
      if (ow1 > w2 || (ow1 == w2 && oi1 < i2)) { w2 = ow1; i2 = oi1; }
    }
  }

  if (l8 == 0) {
    const float invT = 0.02209708691207961f;  // 1/sqrt(2048)
    const float e1 = expf((w2 - w1) * invT);
    const float g1 = 1.0f / (1.0f + e1);
    const float g2 = e1 * g1;
    out[t * 2 + 0] = (float)i1;
    out[t * 2 + 1] = (float)i2;
    out[2 * NTOK + t * 2 + 0] = g1;
    out[2 * NTOK + t * 2 + 1] = g2;
  }
}

extern "C" void kernel_launch(void* const* d_in, const int* in_sizes, int n_in,
                              void* d_out, int out_size, void* d_ws, size_t ws_size,
                              hipStream_t stream) {
  const float* x = (const float*)d_in[0];     // [4,4096,2048] f32
  const float* emb = (const float*)d_in[1];   // [64,2048] f32
  float* ws = (float*)d_ws;
  float* eT = ws;                                     // 2048*64 floats
  float* dotP = ws + 131072;                          // KSPLIT*NTOK*NE floats
  float* sumP = dotP + (size_t)KSPLIT * NTOK * NE;    // KSPLIT*NTOK floats
  float* sumsqP = sumP + (size_t)KSPLIT * NTOK;       // KSPLIT*NTOK floats
  float* out = (float*)d_out;

  expert_ln_kernel<<<NE, 256, 0, stream>>>(emb, eT);
  router_gemm_kernel<<<KSPLIT * (NTOK / TBLK), 256, 0, stream>>>(
      x, eT, dotP, sumP, sumsqP);
  finalize_kernel<<<NTOK / 32, 256, 0, stream>>>(dotP, sumP, sumsqP, out);
}

// Round 4
// 218.465 us; speedup vs baseline: 1.2022x; 1.2022x over previous
//
#include <hip/hip_runtime.h>
#include <math.h>

#define D 2048
#define NE 64
#define NTOK 16384
#define KSPLIT 4
#define KRANGE (D / KSPLIT)     /* 512 */
#define CHUNK 32                /* k per staging chunk */
#define NCHUNK (KRANGE / CHUNK) /* 16 */
#define TBLK 64                 /* tokens per block */
#define XPAD 68                 /* row stride (floats): 16B-aligned rows, spreads banks */
#define LN_EPS 1e-5f

// ---------------- Kernel A: LayerNorm the expert table, store TRANSPOSED ----------------
__global__ __launch_bounds__(256) void expert_ln_kernel(
    const float* __restrict__ emb, float* __restrict__ eT) {
  const int e = blockIdx.x;
  const int tid = threadIdx.x;
  const float4* row = (const float4*)(emb + (size_t)e * D);
  float4 v0 = row[tid * 2];
  float4 v1 = row[tid * 2 + 1];
  float s = v0.x + v0.y + v0.z + v0.w + v1.x + v1.y + v1.z + v1.w;
  float q = v0.x * v0.x + v0.y * v0.y + v0.z * v0.z + v0.w * v0.w
          + v1.x * v1.x + v1.y * v1.y + v1.z * v1.z + v1.w * v1.w;
  #pragma unroll
  for (int off = 32; off > 0; off >>= 1) {
    s += __shfl_down(s, off);
    q += __shfl_down(q, off);
  }
  __shared__ float red[8];
  const int wid = tid >> 6;
  const int lane = tid & 63;
  if (lane == 0) { red[wid] = s; red[4 + wid] = q; }
  __syncthreads();
  if (tid == 0) {
    red[0] = red[0] + red[1] + red[2] + red[3];
    red[4] = red[4] + red[5] + red[6] + red[7];
  }
  __syncthreads();
  const float mu = red[0] * (1.0f / D);
  const float var = red[4] * (1.0f / D) - mu * mu;
  const float sc = rsqrtf(var + LN_EPS);
  float vals[8] = {v0.x, v0.y, v0.z, v0.w, v1.x, v1.y, v1.z, v1.w};
  const int k0 = tid * 8;
  #pragma unroll
  for (int j = 0; j < 8; ++j) {
    eT[(size_t)(k0 + j) * NE + e] = (vals[j] - mu) * sc;
  }
}

// ---------------- Kernel B: K-split GEMM, 64tok x 64exp block, 4x4 thread tile ----------------
// Grid: KSPLIT * 256 token tiles = 1024 blocks (4/CU). Per k per thread:
// 1 ds_read_b128 (x, 16 addr x 4-way bcast) + 1 ds_read_b128 (e, 4 addr x 16-way
// bcast) + 16 FMA -> VALU-bound. Global prefetch software-pipelined one chunk ahead.
__global__ __launch_bounds__(256, 4) void router_gemm_kernel(
    const float* __restrict__ x, const float* __restrict__ eT,
    float* __restrict__ dotP, float* __restrict__ sumP,
    float* __restrict__ sumsqP) {
  __shared__ float xT[CHUNK][XPAD];
  __shared__ float eS[CHUNK][NE];
  const int tid = threadIdx.x;
  const int bt = blockIdx.x & 255;  // token tile (consecutive blocks share kc)
  const int kc = blockIdx.x >> 8;   // K-slice
  const int K0 = kc * KRANGE;
  const int tg = tid & 15;          // token group: tokens tg*4..+4
  const int eg = tid >> 4;          // expert group: experts eg*4..+4

  // staging coords: x-chunk is 64 tok x 32 k = 512 float4; thread does idx=tid, tid+256
  const int stokA = tid >> 3;        // 0..31   (i=0 half)
  const int skq = tid & 7;           // float4 slot within 32-k row
  // e-chunk 32 k x 64 e = 512 float4
  const int sekA = tid >> 4;         // 0..15   (i=0 half)
  const int seq = tid & 15;

  float acc[4][4];
  #pragma unroll
  for (int i = 0; i < 4; ++i)
    #pragma unroll
    for (int j = 0; j < 4; ++j) acc[i][j] = 0.f;
  float sA = 0.f, qA = 0.f, sB = 0.f, qB = 0.f;

  const float* xbase = x + (size_t)bt * TBLK * D + K0;
  const float* ebase = eT + (size_t)K0 * NE;

  // preload chunk 0
  float4 px0 = *(const float4*)(xbase + (size_t)stokA * D + skq * 4);
  float4 px1 = *(const float4*)(xbase + (size_t)(stokA + 32) * D + skq * 4);
  float4 pe0 = *(const float4*)(ebase + (size_t)sekA * NE + seq * 4);
  float4 pe1 = *(const float4*)(ebase + (size_t)(sekA + 16) * NE + seq * 4);

  for (int c = 0; c < NCHUNK; ++c) {
    __syncthreads();  // all waves done reading LDS from chunk c-1
    // token stats from the registers being staged
    sA += px0.x + px0.y + px0.z + px0.w;
    qA += px0.x * px0.x + px0.y * px0.y + px0.z * px0.z + px0.w * px0.w;
    sB += px1.x + px1.y + px1.z + px1.w;
    qB += px1.x * px1.x + px1.y * px1.y + px1.z * px1.z + px1.w * px1.w;
    // transpose-write x into LDS
    xT[skq * 4 + 0][stokA] = px0.x;
    xT[skq * 4 + 1][stokA] = px0.y;
    xT[skq * 4 + 2][stokA] = px0.z;
    xT[skq * 4 + 3][stokA] = px0.w;
    xT[skq * 4 + 0][stokA + 32] = px1.x;
    xT[skq * 4 + 1][stokA + 32] = px1.y;
    xT[skq * 4 + 2][stokA + 32] = px1.z;
    xT[skq * 4 + 3][stokA + 32] = px1.w;
    *(float4*)&eS[sekA][seq * 4] = pe0;
    *(float4*)&eS[sekA + 16][seq * 4] = pe1;
    __syncthreads();
    // issue next chunk's global loads (consumed next iteration -> latency hidden)
    if (c + 1 < NCHUNK) {
      const int off = (c + 1) * CHUNK;
      px0 = *(const float4*)(xbase + (size_t)stokA * D + off + skq * 4);
      px1 = *(const float4*)(xbase + (size_t)(stokA + 32) * D + off + skq * 4);
      pe0 = *(const float4*)(ebase + (size_t)(off + sekA) * NE + seq * 4);
      pe1 = *(const float4*)(ebase + (size_t)(off + sekA + 16) * NE + seq * 4);
    }
    // compute: 32 k x (4 tok x 4 exp)
    #pragma unroll 8
    for (int kk = 0; kk < CHUNK; ++kk) {
      const float4 a = *(const float4*)&xT[kk][tg * 4];
      const float4 b = *(const float4*)&eS[kk][eg * 4];
      const float ar[4] = {a.x, a.y, a.z, a.w};
      const float br[4] = {b.x, b.y, b.z, b.w};
      #pragma unroll
      for (int i = 0; i < 4; ++i)
        #pragma unroll
        for (int j = 0; j < 4; ++j)
          acc[i][j] = fmaf(ar[i], br[j], acc[i][j]);
    }
  }

  // dot partials: [kc][token][expert] (registers only, no LDS dependency)
  {
    float* dp = dotP + ((size_t)kc * NTOK + (size_t)bt * TBLK + tg * 4) * NE + eg * 4;
    #pragma unroll
    for (int i = 0; i < 4; ++i) {
      *(float4*)(dp + (size_t)i * NE) =
          make_float4(acc[i][0], acc[i][1], acc[i][2], acc[i][3]);
    }
  }

  // token stats reduction: 8 partial-holders per token (skq 0..7)
  __syncthreads();  // done with xT/eS as tiles
  float* r1 = &xT[0][0];          // 512 floats
  float* r2 = &xT[0][0] + 512;    // 512 floats (xT has 32*68=2176)
  r1[skq * 64 + stokA] = sA;
  r1[skq * 64 + 32 + stokA] = sB;
  r2[skq * 64 + stokA] = qA;
  r2[skq * 64 + 32 + stokA] = qB;
  __syncthreads();
  if (tid < TBLK) {
    float s = 0.f, q = 0.f;
    #pragma unroll
    for (int j = 0; j < 8; ++j) {
      s += r1[j * 64 + tid];
      q += r2[j * 64 + tid];
    }
    const int gt = bt * TBLK + tid;
    sumP[kc * NTOK + gt] = s;
    sumsqP[kc * NTOK + gt] = q;
  }
}

// ---------------- Kernel C: reduce partials, top-2, softmax gates ----------------
// 8 lanes per token; 32 tokens per 256-thread block; grid = 512 blocks.
__global__ __launch_bounds__(256) void finalize_kernel(
    const float* __restrict__ dotP, const float* __restrict__ sumP,
    const float* __restrict__ sumsqP, float* __restrict__ out) {
  const int tid = threadIdx.x;
  const int t = blockIdx.x * 32 + (tid >> 3);
  const int l8 = tid & 7;

  float s1 = 0.f, s2 = 0.f;
  #pragma unroll
  for (int kc = 0; kc < KSPLIT; ++kc) {
    s1 += sumP[kc * NTOK + t];
    s2 += sumsqP[kc * NTOK + t];
  }
  const float mu = s1 * (1.0f / D);
  const float var = s2 * (1.0f / D) - mu * mu;
  const float sc = rsqrtf(var + LN_EPS);  // sim = dot * sc (sum(e_norm)==0)

  float d[8] = {0.f, 0.f, 0.f, 0.f, 0.f, 0.f, 0.f, 0.f};
  #pragma unroll
  for (int kc = 0; kc < KSPLIT; ++kc) {
    const float* dp = dotP + ((size_t)kc * NTOK + t) * NE + l8 * 8;
    float4 a = *(const float4*)dp;
    float4 b = *(const float4*)(dp + 4);
    d[0] += a.x; d[1] += a.y; d[2] += a.z; d[3] += a.w;
    d[4] += b.x; d[5] += b.y; d[6] += b.z; d[7] += b.w;
  }

  float w1 = -INFINITY, w2 = -INFINITY;
  int i1 = 0, i2 = 0;
  #pragma unroll
  for (int j = 0; j < 8; ++j) {
    const float v = d[j] * sc;
    const int e = l8 * 8 + j;
    if (v > w1) { w2 = w1; i2 = i1; w1 = v; i1 = e; }
    else if (v > w2) { w2 = v; i2 = e; }
  }
  // butterfly merge of (top1, top2) across the 8 lanes of this token
  #pragma unroll
  for (int off = 1; off < 8; off <<= 1) {
    const float ow1 = __shfl_xor(w1, off);
    const float ow2 = __shfl_xor(w2, off);
    const int oi1 = __shfl_xor(i1, off);
    const int oi2 = __shfl_xor(i2, off);
    if (ow1 > w1 || (ow1 == w1 && oi1 < i1)) {
      float nw2; int ni2;
      if (w1 > ow2 || (w1 == ow2 && i1 < oi2)) { nw2 = w1; ni2 = i1; }
      else { nw2 = ow2; ni2 = oi2; }
      w1 = ow1; i1 = oi1; w2 = nw2; i2 = ni2;
    } else {
      if (ow1 > w2 || (ow1 == w2 && oi1 < i2)) { w2 = ow1; i2 = oi1; }
    }
  }

  if (l8 == 0) {
    const float invT = 0.02209708691207961f;  // 1/sqrt(2048)
    const float e1 = expf((w2 - w1) * invT);
    const float g1 = 1.0f / (1.0f + e1);
    const float g2 = e1 * g1;
    out[t * 2 + 0] = (float)i1;
    out[t * 2 + 1] = (float)i2;
    out[2 * NTOK + t * 2 + 0] = g1;
    out[2 * NTOK + t * 2 + 1] = g2;
  }
}

extern "C" void kernel_launch(void* const* d_in, const int* in_sizes, int n_in,
                              void* d_out, int out_size, void* d_ws, size_t ws_size,
                              hipStream_t stream) {
  const float* x = (const float*)d_in[0];     // [4,4096,2048] f32
  const float* emb = (const float*)d_in[1];   // [64,2048] f32
  float* ws = (float*)d_ws;
  float* eT = ws;                                     // 2048*64 floats
  float* dotP = ws + 131072;                          // KSPLIT*NTOK*NE floats
  float* sumP = dotP + (size_t)KSPLIT * NTOK * NE;    // KSPLIT*NTOK floats
  float* sumsqP = sumP + (size_t)KSPLIT * NTOK;       // KSPLIT*NTOK floats
  float* out = (float*)d_out;

  expert_ln_kernel<<<NE, 256, 0, stream>>>(emb, eT);
  router_gemm_kernel<<<KSPLIT * (NTOK / TBLK), 256, 0, stream>>>(
      x, eT, dotP, sumP, sumsqP);
  finalize_kernel<<<NTOK / 32, 256, 0, stream>>>(dotP, sumP, sumsqP, out);
}